// Round 12
// baseline (246.578 us; speedup 1.0000x reference)
//
#include <hip/hip_runtime.h>
#include <hip/hip_bf16.h>

#define HID 128
#define BSH 6            // 64 nodes per bucket
#define MAXBUCK 2048     // >= ceil(n/64); n=100000 -> 1563
#define NSB 512          // edge chunks (binscatter blocks)
#define CAP 2816         // per-bucket LDS edge capacity in agg (mean 2048)

__device__ __forceinline__ float b2f(unsigned short u) {
    union { unsigned i; float f; } v; v.i = ((unsigned)u) << 16; return v.f;
}
__device__ __forceinline__ unsigned short f2b(float f) {
    unsigned u = __float_as_uint(f);
    return (unsigned short)((u + 0x7fffu + ((u >> 16) & 1u)) >> 16);  // RNE
}

// ---------------- K1: per-chunk bucket histogram ----------------
__global__ __launch_bounds__(256) void histblk_kernel(const int* __restrict__ ei,
                                                      unsigned* __restrict__ hist,
                                                      int E, int n, int nbuck) {
    __shared__ unsigned h[MAXBUCK];
    for (int i = threadIdx.x; i < nbuck; i += 256) h[i] = 0u;
    __syncthreads();
    int blk = blockIdx.x;
    int chunk = (E + NSB - 1) / NSB;
    int beg = blk * chunk, end = min(E, beg + chunk);
    for (int i = beg + threadIdx.x; i < end; i += 256) {
        int dst = ei[(size_t)E + i];
        if ((unsigned)dst < (unsigned)n) atomicAdd(&h[dst >> BSH], 1u);
    }
    __syncthreads();
    for (int b = threadIdx.x; b < nbuck; b += 256)
        hist[(size_t)blk * nbuck + b] = h[b];
}

// ---------------- K2: per-bucket exclusive scan over the NSB chunks ----------------
__global__ __launch_bounds__(256) void scan2d_kernel(const unsigned* __restrict__ hist,
                                                     unsigned* __restrict__ base_rel,
                                                     unsigned* __restrict__ bcount,
                                                     int nbuck) {
    int b = blockIdx.x;
    int t = threadIdx.x;
    unsigned v0 = hist[(size_t)(2 * t) * nbuck + b];
    unsigned v1 = hist[(size_t)(2 * t + 1) * nbuck + b];
    unsigned pair = v0 + v1;
    int lane = t & 63, w = t >> 6;
    unsigned x = pair;
    for (int d = 1; d < 64; d <<= 1) {
        unsigned y = __shfl_up(x, d, 64);
        if (lane >= d) x += y;
    }
    __shared__ unsigned wsum[4];
    if (lane == 63) wsum[w] = x;
    __syncthreads();
    unsigned add = 0;
    for (int ww = 0; ww < 4; ++ww) if (ww < w) add += wsum[ww];
    unsigned incl = x + add;
    unsigned excl = incl - pair;
    base_rel[(size_t)(2 * t) * nbuck + b] = excl;
    base_rel[(size_t)(2 * t + 1) * nbuck + b] = excl + v0;
    if (t == 255) bcount[b] = incl;
}

// ---------------- K3: scan of bucket counts (single block) ----------------
__global__ __launch_bounds__(1024) void bscan_kernel(const unsigned* __restrict__ bcount,
                                                     unsigned* __restrict__ boff,
                                                     int nbuck) {
    __shared__ unsigned sums[1024];
    int t = threadIdx.x;
    int chunk = (nbuck + 1023) >> 10;
    int beg = min(t * chunk, nbuck), end = min(beg + chunk, nbuck);
    unsigned local = 0;
    for (int i = beg; i < end; ++i) local += bcount[i];
    sums[t] = local;
    __syncthreads();
    for (int d = 1; d < 1024; d <<= 1) {
        unsigned v = (t >= d) ? sums[t - d] : 0u;
        __syncthreads();
        sums[t] += v;
        __syncthreads();
    }
    unsigned run = (t > 0) ? sums[t - 1] : 0u;
    for (int i = beg; i < end; ++i) { boff[i] = run; run += bcount[i]; }
    if (t == 1023) boff[nbuck] = sums[1023];
}

// ---------------- K4 (fused): single-pass binscatter (blocks 0..NSB-1) + 32-row gemm ----------------
// binned[pos] = (dst&63)<<20 | src ; gemm: hp = (x+h_cur)@W[:,0:128] bf16 flat [n][128]
__global__ __launch_bounds__(256) void phase3_kernel(const int* __restrict__ ei,
                                                     const unsigned* __restrict__ boff,
                                                     const unsigned* __restrict__ base_rel,
                                                     unsigned* __restrict__ binned,
                                                     const float* __restrict__ x,
                                                     const float* __restrict__ hc,
                                                     const float* __restrict__ W,
                                                     unsigned short* __restrict__ hp,
                                                     int E, int n, int nbuck) {
    __shared__ union {
        unsigned cursor[MAXBUCK];   // 8 KB
        float A[32 * 132];          // 16.9 KB
    } sm;

    if (blockIdx.x < NSB) {
        // ---- binscatter: single pass, no global atomics ----
        int blk = blockIdx.x;
        for (int b = threadIdx.x; b < nbuck; b += 256)
            sm.cursor[b] = boff[b] + base_rel[(size_t)blk * nbuck + b];
        __syncthreads();
        int chunk = (E + NSB - 1) / NSB;
        int beg = blk * chunk, end = min(E, beg + chunk);
        for (int i = beg + threadIdx.x; i < end; i += 256) {
            int s = ei[i];
            int dst = ei[(size_t)E + i];
            if ((unsigned)dst >= (unsigned)n) continue;
            unsigned ss = (unsigned)min(max(s, 0), n - 1);
            unsigned slot = atomicAdd(&sm.cursor[dst >> BSH], 1u);
            binned[slot] = ss | ((unsigned)(dst & ((1 << BSH) - 1)) << 20);
        }
    } else {
        // ---- gemm: 32-row tile ----
        int tid = threadIdx.x;
        int r0 = (blockIdx.x - NSB) * 32;

        for (int i = tid; i < 1024; i += 256) {
            int row = i >> 5;
            int c4 = (i & 31) * 4;
            int grow = r0 + row;
            float4 v;
            if (grow < n) {
                float4 a = *(const float4*)(x + (size_t)grow * HID + c4);
                float4 bb = *(const float4*)(hc + (size_t)grow * HID + c4);
                v = make_float4(a.x + bb.x, a.y + bb.y, a.z + bb.z, a.w + bb.w);
            } else {
                v = make_float4(0.f, 0.f, 0.f, 0.f);
            }
            *(float4*)(&sm.A[row * 132 + c4]) = v;
        }
        __syncthreads();

        int cg = tid & 31;
        int c4 = cg * 4;
        int rg = tid >> 5;
        float acc[4][4];
#pragma unroll
        for (int r = 0; r < 4; ++r) {
            acc[r][0] = 0.f; acc[r][1] = 0.f; acc[r][2] = 0.f; acc[r][3] = 0.f;
        }

#pragma unroll 4
        for (int k = 0; k < 128; ++k) {
            float4 w = *(const float4*)(W + (size_t)k * 512 + c4);
#pragma unroll
            for (int r = 0; r < 4; ++r) {
                float a = sm.A[(rg * 4 + r) * 132 + k];
                acc[r][0] += a * w.x;
                acc[r][1] += a * w.y;
                acc[r][2] += a * w.z;
                acc[r][3] += a * w.w;
            }
        }

#pragma unroll
        for (int r = 0; r < 4; ++r) {
            int grow = r0 + rg * 4 + r;
            if (grow < n) {
                unsigned long long pack =
                    (unsigned long long)f2b(acc[r][0]) |
                    ((unsigned long long)f2b(acc[r][1]) << 16) |
                    ((unsigned long long)f2b(acc[r][2]) << 32) |
                    ((unsigned long long)f2b(acc[r][3]) << 48);
                *(unsigned long long*)(hp + (size_t)grow * HID + c4) = pack;
            }
        }
    }
}

// ---------------- K5: per-bucket degree -> off[node], dinv[node] ----------------
__global__ __launch_bounds__(256) void csrlite_kernel(const unsigned* __restrict__ binned,
                                                      const unsigned* __restrict__ boff,
                                                      unsigned* __restrict__ off,
                                                      float* __restrict__ dinv, int n) {
    __shared__ unsigned hist[64];
    int b = blockIdx.x;
    int t = threadIdx.x;
    if (t < 64) hist[t] = 0u;
    __syncthreads();
    unsigned s0 = boff[b], s1 = boff[b + 1];
    for (unsigned j = s0 + t; j < s1; j += 256) atomicAdd(&hist[binned[j] >> 20], 1u);
    __syncthreads();
    if (t < 64) {
        unsigned cnt = hist[t];
        unsigned x = cnt;
        for (int d = 1; d < 64; d <<= 1) {
            unsigned v = __shfl_up(x, d, 64);
            if (t >= d) x += v;
        }
        unsigned excl = x - cnt;
        int node = (b << BSH) + t;
        if (node < n) {
            off[node] = s0 + excl;
            dinv[node] = rsqrtf((float)(cnt + 1u));  // +1 self-loop
        }
    }
}

// ---------------- K6: merged placement + aggregate (one bucket per block) ----------------
__global__ __launch_bounds__(256) void agg_merged_kernel(const unsigned* __restrict__ binned,
                                                         const unsigned* __restrict__ boff,
                                                         const unsigned* __restrict__ off,
                                                         const float* __restrict__ dinv,
                                                         const unsigned short* __restrict__ hp,
                                                         const float* __restrict__ bias,
                                                         float* __restrict__ out, int n) {
    __shared__ unsigned srcs_lds[CAP];
    __shared__ unsigned nodeoff[65];
    __shared__ unsigned cursor[64];
    __shared__ float sdinv[64];
    int b = blockIdx.x;
    int tid = threadIdx.x;
    unsigned s0 = boff[b], s1 = boff[b + 1];
    unsigned cnt = s1 - s0;
    int node0 = b << BSH;

    if (tid < 64) {
        int node = node0 + tid;
        unsigned o = (node < n) ? off[node] : s1;
        nodeoff[tid] = o - s0;
        cursor[tid] = o - s0;
        sdinv[tid] = (node < n) ? dinv[node] : 0.f;
    }
    if (tid == 64) nodeoff[64] = cnt;
    __syncthreads();

    if (cnt <= CAP) {
        for (unsigned j = s0 + tid; j < s1; j += 256) {
            unsigned p = binned[j];
            unsigned slot = atomicAdd(&cursor[p >> 20], 1u);
            srcs_lds[slot] = p & 0xFFFFFu;
        }
        __syncthreads();

        int w = tid >> 6, lane = tid & 63;
        int c = lane * 2;
        for (int nl = w * 16; nl < w * 16 + 16; ++nl) {
            int node = node0 + nl;
            if (node >= n) break;
            unsigned beg = nodeoff[nl], end2 = nodeoff[nl + 1];
            float ax = 0.f, ay = 0.f;
            unsigned i = beg;
            for (; i + 8 <= end2; i += 8) {
                unsigned s[8]; float wd[8]; ushort2 v[8];
#pragma unroll
                for (int j = 0; j < 8; ++j) s[j] = srcs_lds[i + j];
#pragma unroll
                for (int j = 0; j < 8; ++j) wd[j] = dinv[s[j]];
#pragma unroll
                for (int j = 0; j < 8; ++j) v[j] = *(const ushort2*)(hp + ((size_t)s[j] << 7) + c);
#pragma unroll
                for (int j = 0; j < 8; ++j) { ax += wd[j] * b2f(v[j].x); ay += wd[j] * b2f(v[j].y); }
            }
            if (i < end2) {
                unsigned last = end2 - 1;
                unsigned s[8]; float wd[8]; ushort2 v[8];
#pragma unroll
                for (int j = 0; j < 8; ++j) {
                    unsigned jj = i + j;
                    s[j] = srcs_lds[jj < end2 ? jj : last];
                    wd[j] = (jj < end2) ? 1.f : 0.f;
                }
#pragma unroll
                for (int j = 0; j < 8; ++j) wd[j] *= dinv[s[j]];
#pragma unroll
                for (int j = 0; j < 8; ++j) v[j] = *(const ushort2*)(hp + ((size_t)s[j] << 7) + c);
#pragma unroll
                for (int j = 0; j < 8; ++j) { ax += wd[j] * b2f(v[j].x); ay += wd[j] * b2f(v[j].y); }
            }
            float dd = sdinv[nl];
            ushort2 hd = *(const ushort2*)(hp + ((size_t)node << 7) + c);
            ax += dd * b2f(hd.x);
            ay += dd * b2f(hd.y);
            float2 bb = *(const float2*)(bias + c);
            float2 res = make_float2(dd * ax + bb.x, dd * ay + bb.y);
            *(float2*)(out + ((size_t)node << 7) + c) = res;
        }
    } else {
        // correctness-only fallback (never triggers for this data)
        for (int idx = tid; idx < 64 * HID; idx += 256) {
            int ndl = idx >> 7, col = idx & (HID - 1);
            int node = node0 + ndl;
            if (node < n) {
                float dd = sdinv[ndl];
                out[((size_t)node << 7) + col] = dd * dd * b2f(hp[((size_t)node << 7) + col]) + bias[col];
            }
        }
        __syncthreads();
        if (tid < 64) {
            int c = tid * 2;
            for (unsigned j = s0; j < s1; ++j) {
                unsigned p = binned[j];
                unsigned dl = p >> 20, s = p & 0xFFFFFu;
                float wsc = dinv[s] * sdinv[dl];
                ushort2 v = *(const ushort2*)(hp + ((size_t)s << 7) + c);
                float2* o = (float2*)(out + ((size_t)(node0 + dl) << 7) + c);
                float2 cur = *o;
                cur.x += wsc * b2f(v.x);
                cur.y += wsc * b2f(v.y);
                *o = cur;
            }
        }
    }
}

extern "C" void kernel_launch(void* const* d_in, const int* in_sizes, int n_in,
                              void* d_out, int out_size, void* d_ws, size_t ws_size,
                              hipStream_t stream) {
    const float* x = (const float*)d_in[0];
    const int* ei = (const int*)d_in[1];       // int32 per harness contract
    const float* hc = (const float*)d_in[2];
    // d_in[3] = c_cur unused
    const float* W = (const float*)d_in[4];
    const float* b = (const float*)d_in[5];
    float* out = (float*)d_out;

    int n = in_sizes[0] / HID;      // 100000
    int E = in_sizes[1] / 2;        // 3200000
    int nbuck = (n + 63) >> BSH;    // 1563 (<= MAXBUCK)

    // workspace layout (16B-aligned), total ~39.2 MB
    char* ws = (char*)d_ws;
    unsigned* bcount = (unsigned*)(ws);                    // 8KB region
    unsigned* boff   = (unsigned*)(ws + 8192);             // 8KB region (nbuck+1)
    unsigned* off    = (unsigned*)(ws + 24576);            // n*4 = 400000
    float*    dinv   = (float*)   (ws + 424576);           // n*4
    unsigned* binned = (unsigned*)(ws + 824576);           // E*4 = 12.8MB
    unsigned short* hp = (unsigned short*)(ws + 13624576); // [n][128] bf16 = 25.6MB

    // d_out doubles as scratch for hist/base_rel (6.4MB << 51.2MB);
    // agg_merged fully overwrites d_out afterwards.
    unsigned* hist     = (unsigned*)d_out;                 // [NSB][nbuck]
    unsigned* base_rel = hist + (size_t)NSB * nbuck;       // [NSB][nbuck]

    histblk_kernel<<<NSB, 256, 0, stream>>>(ei, hist, E, n, nbuck);
    scan2d_kernel<<<nbuck, 256, 0, stream>>>(hist, base_rel, bcount, nbuck);
    bscan_kernel<<<1, 1024, 0, stream>>>(bcount, boff, nbuck);

    int gemm_blocks = (n + 31) / 32;   // 3125
    phase3_kernel<<<NSB + gemm_blocks, 256, 0, stream>>>(ei, boff, base_rel, binned,
                                                         x, hc, W, hp, E, n, nbuck);
    csrlite_kernel<<<nbuck, 256, 0, stream>>>(binned, boff, off, dinv, n);
    agg_merged_kernel<<<nbuck, 256, 0, stream>>>(binned, boff, off, dinv, hp, b, out, n);
}